// Round 1
// baseline (13222.659 us; speedup 1.0000x reference)
//
#include <hip/hip_runtime.h>
#include <math.h>

// ---------------- problem constants ----------------
constexpr int   NN  = 100000;    // nodes
constexpr int   EE  = 1600000;   // edges
constexpr int   HH  = 128;       // hidden / in_channels
constexpr int   GG  = 128;       // graphs
constexpr float EPSV = 1e-5f;

// ---------------- workspace layout ----------------
constexpr size_t A256(size_t x) { return (x + 255) & ~(size_t)255; }
constexpr size_t OFF_DEG = 0;                                       // N floats (deg -> dinv in place)
constexpr size_t OFF_RP  = A256(OFF_DEG + (size_t)NN * 4);          // (N+1) ints row_ptr
constexpr size_t OFF_CUR = A256(OFF_RP  + (size_t)(NN + 1) * 4);    // N ints cursor
constexpr size_t OFF_SRC = A256(OFF_CUR + (size_t)NN * 4);          // E ints sorted src
constexpr size_t OFF_BS  = A256(OFF_SRC + (size_t)EE * 4);          // 512 ints block sums
constexpr size_t OFF_B0  = A256(OFF_BS  + 512 * 4);                 // N*H floats
constexpr size_t OFF_B1  = A256(OFF_B0  + (size_t)NN * HH * 4);     // N*H floats
constexpr size_t OFF_PL  = A256(OFF_B1  + (size_t)NN * HH * 4);     // G*H floats pooled + G floats cnt

// ---------------- degree / CSR build ----------------
__global__ void k_init_deg(float* deg) {
    int i = blockIdx.x * 256 + threadIdx.x;
    if (i < NN) deg[i] = 1.0f;  // self-loop
}

__global__ void k_count(const int* __restrict__ dst, float* __restrict__ deg) {
    int e = blockIdx.x * 256 + threadIdx.x;
    if (e < EE) atomicAdd(&deg[dst[e]], 1.0f);
}

__global__ __launch_bounds__(1024) void k_scan_local(const float* __restrict__ deg,
                                                     int* __restrict__ row_ptr,
                                                     int* __restrict__ bsum) {
    __shared__ int s[1024];
    int t = threadIdx.x;
    int i = blockIdx.x * 1024 + t;
    int v = 0;
    if (i < NN) v = (int)deg[i] - 1;   // edge count (deg exact small integer)
    s[t] = v;
    __syncthreads();
    for (int off = 1; off < 1024; off <<= 1) {
        int u = (t >= off) ? s[t - off] : 0;
        __syncthreads();
        s[t] += u;
        __syncthreads();
    }
    if (i < NN) row_ptr[i] = s[t] - v;          // exclusive
    if (t == 1023) bsum[blockIdx.x] = s[1023];  // block total
}

__global__ void k_scan_blocks(int* __restrict__ bsum, int nb) {
    __shared__ int s[128];
    int t = threadIdx.x;
    int v = (t < nb) ? bsum[t] : 0;
    s[t] = v;
    __syncthreads();
    for (int off = 1; off < 128; off <<= 1) {
        int u = (t >= off) ? s[t - off] : 0;
        __syncthreads();
        s[t] += u;
        __syncthreads();
    }
    if (t < nb) bsum[t] = s[t] - v;  // exclusive block offsets
}

__global__ void k_scan_add(int* __restrict__ row_ptr, const int* __restrict__ bsum) {
    int i = blockIdx.x * 256 + threadIdx.x;
    if (i < NN) row_ptr[i] += bsum[i >> 10];
    if (i == 0) row_ptr[NN] = EE;
}

__global__ void k_dinv(float* __restrict__ deg) {
    int i = blockIdx.x * 256 + threadIdx.x;
    if (i < NN) deg[i] = rsqrtf(deg[i]);  // deg >= 1 always
}

__global__ void k_scatter(const int* __restrict__ src, const int* __restrict__ dst,
                          const int* __restrict__ row_ptr, int* __restrict__ cursor,
                          int* __restrict__ ssrc) {
    int e = blockIdx.x * 256 + threadIdx.x;
    if (e < EE) {
        int d = dst[e];
        int p = atomicAdd(&cursor[d], 1);
        ssrc[row_ptr[d] + p] = src[e];
    }
}

// ---------------- GEMM: C[N,128] = A[N,128] @ W[128,128] ----------------
__global__ __launch_bounds__(256) void gemm128(const float* __restrict__ A,
                                               const float* __restrict__ W,
                                               float* __restrict__ C, int nrows) {
    __shared__ float As[64][128];  // As[k][r] (transposed tile)
    __shared__ float Bs[64][128];  // Bs[k][c]
    int t  = threadIdx.x;
    int tx = t & 15, ty = t >> 4;
    int row0 = blockIdx.x * 128;
    float acc[8][8] = {};

    for (int k0 = 0; k0 < 128; k0 += 64) {
        // stage A tile (128 rows x 64 k), transposed into LDS
#pragma unroll
        for (int i = 0; i < 8; ++i) {
            int idx = t + i * 256;       // 0..2047
            int r   = idx >> 4;          // 0..127
            int kq  = idx & 15;          // 0..15 -> k quad
            float4 v = make_float4(0.f, 0.f, 0.f, 0.f);
            int row = row0 + r;
            if (row < nrows) v = *(const float4*)(A + (size_t)row * 128 + k0 + kq * 4);
            As[kq * 4 + 0][r] = v.x;
            As[kq * 4 + 1][r] = v.y;
            As[kq * 4 + 2][r] = v.z;
            As[kq * 4 + 3][r] = v.w;
        }
        // stage W tile (64 k x 128 cols)
#pragma unroll
        for (int i = 0; i < 8; ++i) {
            int idx = t + i * 256;       // 0..2047
            int kk  = idx >> 5;          // 0..63
            int cq  = idx & 31;          // 0..31
            *(float4*)(&Bs[kk][cq * 4]) = *(const float4*)(W + (size_t)(k0 + kk) * 128 + cq * 4);
        }
        __syncthreads();
#pragma unroll
        for (int k = 0; k < 64; ++k) {
            float a[8], b[8];
            ((float4*)a)[0] = *(const float4*)(&As[k][ty * 8]);
            ((float4*)a)[1] = *(const float4*)(&As[k][ty * 8 + 4]);
            ((float4*)b)[0] = *(const float4*)(&Bs[k][tx * 8]);
            ((float4*)b)[1] = *(const float4*)(&Bs[k][tx * 8 + 4]);
#pragma unroll
            for (int i = 0; i < 8; ++i)
#pragma unroll
                for (int j = 0; j < 8; ++j)
                    acc[i][j] = fmaf(a[i], b[j], acc[i][j]);
        }
        __syncthreads();
    }
#pragma unroll
    for (int i = 0; i < 8; ++i) {
        int row = row0 + ty * 8 + i;
        if (row < nrows) {
            float4 v0 = make_float4(acc[i][0], acc[i][1], acc[i][2], acc[i][3]);
            float4 v1 = make_float4(acc[i][4], acc[i][5], acc[i][6], acc[i][7]);
            *(float4*)(C + (size_t)row * 128 + tx * 8)     = v0;
            *(float4*)(C + (size_t)row * 128 + tx * 8 + 4) = v1;
        }
    }
}

// ---------------- aggregate + bias + BN + ReLU ----------------
// one wave per node, 2 channels per lane; edges processed 8-wide for MLP
__global__ __launch_bounds__(256) void k_agg(const float* __restrict__ hw,
                                             const int* __restrict__ rp,
                                             const int* __restrict__ ssrc,
                                             const float* __restrict__ dinv,
                                             const float* __restrict__ bsl,
                                             const float* __restrict__ gamma,
                                             const float* __restrict__ beta,
                                             const float* __restrict__ rm,
                                             const float* __restrict__ rv,
                                             float* __restrict__ out) {
    int lane = threadIdx.x & 63;
    int n = blockIdx.x * 4 + (threadIdx.x >> 6);
    if (n >= NN) return;
    int beg = rp[n], end = rp[n + 1];
    int c = lane * 2;
    float ax = 0.f, ay = 0.f;
    for (int e = beg; e < end; e += 8) {
        float ds[8];
        const float2* vp[8];
#pragma unroll
        for (int i = 0; i < 8; ++i) {
            int ei = e + i;
            int si = (ei < end) ? ei : (end - 1);
            int s = ssrc[si];
            float m = (ei < end) ? 1.0f : 0.0f;
            ds[i] = m * dinv[s];
            vp[i] = (const float2*)(hw + (size_t)s * 128 + c);
        }
#pragma unroll
        for (int i = 0; i < 8; ++i) {
            float2 v = *vp[i];
            ax = fmaf(ds[i], v.x, ax);
            ay = fmaf(ds[i], v.y, ay);
        }
    }
    float di = dinv[n];
    float2 vs = *(const float2*)(hw + (size_t)n * 128 + c);
    ax = fmaf(di, vs.x, ax);
    ay = fmaf(di, vs.y, ay);
    ax *= di;
    ay *= di;
    // y = (agg + b - rm) * gamma*rsqrt(rv+eps) + beta ; relu
    float sc0 = gamma[c]     * rsqrtf(rv[c]     + EPSV);
    float sc1 = gamma[c + 1] * rsqrtf(rv[c + 1] + EPSV);
    float b0 = fmaf(bsl[c]     - rm[c],     sc0, beta[c]);
    float b1 = fmaf(bsl[c + 1] - rm[c + 1], sc1, beta[c + 1]);
    float y0 = fmaxf(fmaf(ax, sc0, b0), 0.f);
    float y1 = fmaxf(fmaf(ay, sc1, b1), 0.f);
    *(float2*)(out + (size_t)n * 128 + c) = make_float2(y0, y1);
}

// ---------------- global mean pool (batch sorted) ----------------
__global__ __launch_bounds__(128) void k_pool(const float* __restrict__ h,
                                              const int* __restrict__ batch,
                                              float* __restrict__ pooled,
                                              float* __restrict__ cnt) {
    int t = threadIdx.x;  // channel
    const int chunk = (NN + 1023) / 1024;  // 98
    int n0 = blockIdx.x * chunk;
    if (n0 >= NN) return;
    int n1 = n0 + chunk;
    if (n1 > NN) n1 = NN;
    int cur = batch[n0];
    float acc = 0.f;
    int k = 0;
    for (int n = n0; n < n1; ++n) {
        int b = batch[n];
        if (b != cur) {
            atomicAdd(&pooled[(size_t)cur * 128 + t], acc);
            if (t == 0) atomicAdd(&cnt[cur], (float)k);
            acc = 0.f; k = 0; cur = b;
        }
        acc += h[(size_t)n * 128 + t];
        ++k;
    }
    atomicAdd(&pooled[(size_t)cur * 128 + t], acc);
    if (t == 0) atomicAdd(&cnt[cur], (float)k);
}

// ---------------- LSTM (single step, h0=c0=0) + FC ----------------
__global__ __launch_bounds__(128) void k_head(const float* __restrict__ pooled,
                                              const float* __restrict__ cnt,
                                              const float* __restrict__ W_ih,
                                              const float* __restrict__ b_ih,
                                              const float* __restrict__ b_hh,
                                              const float* __restrict__ W_fc,
                                              const float* __restrict__ b_fc,
                                              float* __restrict__ out) {
    __shared__ float pm[128];
    __shared__ float gate[512];
    __shared__ float hn[128];
    int g = blockIdx.x, t = threadIdx.x;
    float cdiv = fmaxf(cnt[g], 1.0f);
    pm[t] = pooled[(size_t)g * 128 + t] / cdiv;
    __syncthreads();
    for (int j = t; j < 512; j += 128) {
        float acc = b_ih[j] + b_hh[j];
        const float* w = W_ih + (size_t)j * 128;
#pragma unroll 8
        for (int k = 0; k < 128; ++k) acc = fmaf(pm[k], w[k], acc);
        gate[j] = acc;
    }
    __syncthreads();
    {
        float gi = gate[t], gg = gate[256 + t], go = gate[384 + t];
        float cc = (1.f / (1.f + expf(-gi))) * tanhf(gg);
        hn[t] = (1.f / (1.f + expf(-go))) * tanhf(cc);
    }
    __syncthreads();
    if (t < 16) {
        float acc = b_fc[t];
        const float* w = W_fc + (size_t)t * 128;
#pragma unroll 8
        for (int k = 0; k < 128; ++k) acc = fmaf(hn[k], w[k], acc);
        out[(size_t)g * 16 + t] = acc;
    }
}

// ---------------- launch ----------------
extern "C" void kernel_launch(void* const* d_in, const int* in_sizes, int n_in,
                              void* d_out, int out_size, void* d_ws, size_t ws_size,
                              hipStream_t stream) {
    const float* x      = (const float*)d_in[0];
    const int*   ei     = (const int*)d_in[1];
    const int*   src    = ei;
    const int*   dst    = ei + EE;
    const int*   batch  = (const int*)d_in[2];
    const float* Ws     = (const float*)d_in[3];
    const float* bs     = (const float*)d_in[4];
    const float* gammas = (const float*)d_in[5];
    const float* betas  = (const float*)d_in[6];
    const float* rms    = (const float*)d_in[7];
    const float* rvs    = (const float*)d_in[8];
    const float* W_ih   = (const float*)d_in[9];
    // d_in[10] = W_hh (unused: h0 = 0)
    const float* b_ih   = (const float*)d_in[11];
    const float* b_hh   = (const float*)d_in[12];
    const float* W_fc   = (const float*)d_in[13];
    const float* b_fc   = (const float*)d_in[14];
    float* out = (float*)d_out;

    char* w = (char*)d_ws;
    float* deg    = (float*)(w + OFF_DEG);   // becomes dinv
    int*   rp     = (int*)(w + OFF_RP);
    int*   cursor = (int*)(w + OFF_CUR);
    int*   ssrc   = (int*)(w + OFF_SRC);
    int*   bsum   = (int*)(w + OFF_BS);
    float* buf0   = (float*)(w + OFF_B0);
    float* buf1   = (float*)(w + OFF_B1);
    float* pooled = (float*)(w + OFF_PL);
    float* cntb   = pooled + (size_t)GG * HH;

    hipMemsetAsync(cursor, 0, (size_t)NN * 4, stream);
    hipMemsetAsync(pooled, 0, ((size_t)GG * HH + GG) * 4, stream);

    k_init_deg<<<(NN + 255) / 256, 256, 0, stream>>>(deg);
    k_count<<<(EE + 255) / 256, 256, 0, stream>>>(dst, deg);
    const int nscan = (NN + 1023) / 1024;  // 98
    k_scan_local<<<nscan, 1024, 0, stream>>>(deg, rp, bsum);
    k_scan_blocks<<<1, 128, 0, stream>>>(bsum, nscan);
    k_scan_add<<<(NN + 255) / 256, 256, 0, stream>>>(rp, bsum);
    k_dinv<<<(NN + 255) / 256, 256, 0, stream>>>(deg);
    k_scatter<<<(EE + 255) / 256, 256, 0, stream>>>(src, dst, rp, cursor, ssrc);

    const float* hin = x;
    for (int l = 0; l < 3; ++l) {
        gemm128<<<(NN + 127) / 128, 256, 0, stream>>>(hin, Ws + (size_t)l * 128 * 128, buf1, NN);
        k_agg<<<(NN + 3) / 4, 256, 0, stream>>>(buf1, rp, ssrc, deg,
                                                bs + l * 128, gammas + l * 128, betas + l * 128,
                                                rms + l * 128, rvs + l * 128, buf0);
        hin = buf0;
    }
    k_pool<<<1024, 128, 0, stream>>>(buf0, batch, pooled, cntb);
    k_head<<<GG, 128, 0, stream>>>(pooled, cntb, W_ih, b_ih, b_hh, W_fc, b_fc, out);
}

// Round 2
// 867.936 us; speedup vs baseline: 15.2346x; 15.2346x over previous
//
#include <hip/hip_runtime.h>
#include <math.h>

// ---------------- problem constants ----------------
constexpr int   NN  = 100000;    // nodes
constexpr int   EE  = 1600000;   // edges
constexpr int   HH  = 128;       // hidden / in_channels
constexpr int   GG  = 128;       // graphs
constexpr float EPSV = 1e-5f;

// ---------------- workspace layout ----------------
constexpr size_t A256(size_t x) { return (x + 255) & ~(size_t)255; }
constexpr size_t OFF_DEG = 0;                                       // N floats (deg -> dinv in place)
constexpr size_t OFF_RP  = A256(OFF_DEG + (size_t)NN * 4);          // (N+1) ints row_ptr
constexpr size_t OFF_CUR = A256(OFF_RP  + (size_t)(NN + 1) * 4);    // N ints cursor
constexpr size_t OFF_SRC = A256(OFF_CUR + (size_t)NN * 4);          // E ints sorted src
constexpr size_t OFF_BS  = A256(OFF_SRC + (size_t)EE * 4);          // 512 ints block sums
constexpr size_t OFF_B0  = A256(OFF_BS  + 512 * 4);                 // N*H floats
constexpr size_t OFF_B1  = A256(OFF_B0  + (size_t)NN * HH * 4);     // N*H floats
constexpr size_t OFF_PL  = A256(OFF_B1  + (size_t)NN * HH * 4);     // G*H floats pooled + G floats cnt

// ---------------- degree / CSR build ----------------
__global__ void k_init_deg(float* deg) {
    int i = blockIdx.x * 256 + threadIdx.x;
    if (i < NN) deg[i] = 1.0f;  // self-loop
}

__global__ void k_count(const int* __restrict__ dst, float* __restrict__ deg) {
    int e = blockIdx.x * 256 + threadIdx.x;
    if (e < EE) atomicAdd(&deg[dst[e]], 1.0f);
}

__global__ __launch_bounds__(1024) void k_scan_local(const float* __restrict__ deg,
                                                     int* __restrict__ row_ptr,
                                                     int* __restrict__ bsum) {
    __shared__ int s[1024];
    int t = threadIdx.x;
    int i = blockIdx.x * 1024 + t;
    int v = 0;
    if (i < NN) v = (int)deg[i] - 1;   // edge count (deg exact small integer)
    s[t] = v;
    __syncthreads();
    for (int off = 1; off < 1024; off <<= 1) {
        int u = (t >= off) ? s[t - off] : 0;
        __syncthreads();
        s[t] += u;
        __syncthreads();
    }
    if (i < NN) row_ptr[i] = s[t] - v;          // exclusive
    if (t == 1023) bsum[blockIdx.x] = s[1023];  // block total
}

__global__ void k_scan_blocks(int* __restrict__ bsum, int nb) {
    __shared__ int s[128];
    int t = threadIdx.x;
    int v = (t < nb) ? bsum[t] : 0;
    s[t] = v;
    __syncthreads();
    for (int off = 1; off < 128; off <<= 1) {
        int u = (t >= off) ? s[t - off] : 0;
        __syncthreads();
        s[t] += u;
        __syncthreads();
    }
    if (t < nb) bsum[t] = s[t] - v;  // exclusive block offsets
}

__global__ void k_scan_add(int* __restrict__ row_ptr, const int* __restrict__ bsum) {
    int i = blockIdx.x * 256 + threadIdx.x;
    if (i < NN) row_ptr[i] += bsum[i >> 10];
    if (i == 0) row_ptr[NN] = EE;
}

__global__ void k_dinv(float* __restrict__ deg) {
    int i = blockIdx.x * 256 + threadIdx.x;
    if (i < NN) deg[i] = rsqrtf(deg[i]);  // deg >= 1 always
}

__global__ void k_scatter(const int* __restrict__ src, const int* __restrict__ dst,
                          const int* __restrict__ row_ptr, int* __restrict__ cursor,
                          int* __restrict__ ssrc) {
    int e = blockIdx.x * 256 + threadIdx.x;
    if (e < EE) {
        int d = dst[e];
        int p = atomicAdd(&cursor[d], 1);
        ssrc[row_ptr[d] + p] = src[e];
    }
}

// ---------------- GEMM: C[N,128] = A[N,128] @ W[128,128] ----------------
// 64 rows x 128 cols per block, 256 threads, 4x8 micro-tile, BK=32.
// acc=32 regs; k-loop unrolled 8 only -> VGPR ~<128, NO spill (R1 lesson:
// full 64-unroll + 8x8 tile spilled to scratch -> 5 GB of HBM scratch traffic).
__global__ __launch_bounds__(256) void gemm64(const float* __restrict__ A,
                                              const float* __restrict__ W,
                                              float* __restrict__ C, int nrows) {
    __shared__ float As[32][68];   // k-major (transposed), +4 pad: 16B-aligned rows, <=2-way bank alias
    __shared__ float Bs[32][128];  // k-major (W natural layout)
    int t  = threadIdx.x;
    int tx = t & 15;               // 16 col-groups of 8 cols
    int ty = t >> 4;               // 16 row-groups of 4 rows
    int row0 = blockIdx.x * 64;
    float acc[4][8] = {};

    for (int k0 = 0; k0 < 128; k0 += 32) {
        // stage A tile (64 rows x 32 k), transposed into LDS. 512 float4, 2/thread.
#pragma unroll
        for (int i = 0; i < 2; ++i) {
            int idx = t + i * 256;     // 0..511
            int r   = idx >> 3;        // 0..63
            int kq  = idx & 7;         // 0..7
            float4 v = make_float4(0.f, 0.f, 0.f, 0.f);
            int row = row0 + r;
            if (row < nrows) v = *(const float4*)(A + (size_t)row * 128 + k0 + kq * 4);
            As[kq * 4 + 0][r] = v.x;
            As[kq * 4 + 1][r] = v.y;
            As[kq * 4 + 2][r] = v.z;
            As[kq * 4 + 3][r] = v.w;
        }
        // stage W tile (32 k x 128 cols). 1024 float4, 4/thread, coalesced.
#pragma unroll
        for (int i = 0; i < 4; ++i) {
            int idx = t + i * 256;     // 0..1023
            int kk  = idx >> 5;        // 0..31
            int cq  = idx & 31;        // 0..31
            *(float4*)(&Bs[kk][cq * 4]) = *(const float4*)(W + (size_t)(k0 + kk) * 128 + cq * 4);
        }
        __syncthreads();
#pragma unroll 8
        for (int k = 0; k < 32; ++k) {
            float a4[4], b8[8];
            *(float4*)a4      = *(const float4*)(&As[k][ty * 4]);
            *(float4*)b8      = *(const float4*)(&Bs[k][tx * 8]);
            *(float4*)(b8+4)  = *(const float4*)(&Bs[k][tx * 8 + 4]);
#pragma unroll
            for (int i = 0; i < 4; ++i)
#pragma unroll
                for (int j = 0; j < 8; ++j)
                    acc[i][j] = fmaf(a4[i], b8[j], acc[i][j]);
        }
        __syncthreads();
    }
#pragma unroll
    for (int i = 0; i < 4; ++i) {
        int row = row0 + ty * 4 + i;
        if (row < nrows) {
            float4 v0 = make_float4(acc[i][0], acc[i][1], acc[i][2], acc[i][3]);
            float4 v1 = make_float4(acc[i][4], acc[i][5], acc[i][6], acc[i][7]);
            *(float4*)(C + (size_t)row * 128 + tx * 8)     = v0;
            *(float4*)(C + (size_t)row * 128 + tx * 8 + 4) = v1;
        }
    }
}

// ---------------- aggregate + bias + BN + ReLU ----------------
// one wave per node, 2 channels per lane; edges processed 8-wide for MLP
__global__ __launch_bounds__(256) void k_agg(const float* __restrict__ hw,
                                             const int* __restrict__ rp,
                                             const int* __restrict__ ssrc,
                                             const float* __restrict__ dinv,
                                             const float* __restrict__ bsl,
                                             const float* __restrict__ gamma,
                                             const float* __restrict__ beta,
                                             const float* __restrict__ rm,
                                             const float* __restrict__ rv,
                                             float* __restrict__ out) {
    int lane = threadIdx.x & 63;
    int n = blockIdx.x * 4 + (threadIdx.x >> 6);
    if (n >= NN) return;
    int beg = rp[n], end = rp[n + 1];
    int c = lane * 2;
    float ax = 0.f, ay = 0.f;
    for (int e = beg; e < end; e += 8) {
        float ds[8];
        const float2* vp[8];
#pragma unroll
        for (int i = 0; i < 8; ++i) {
            int ei = e + i;
            int si = (ei < end) ? ei : (end - 1);
            int s = ssrc[si];
            float m = (ei < end) ? 1.0f : 0.0f;
            ds[i] = m * dinv[s];
            vp[i] = (const float2*)(hw + (size_t)s * 128 + c);
        }
#pragma unroll
        for (int i = 0; i < 8; ++i) {
            float2 v = *vp[i];
            ax = fmaf(ds[i], v.x, ax);
            ay = fmaf(ds[i], v.y, ay);
        }
    }
    float di = dinv[n];
    float2 vs = *(const float2*)(hw + (size_t)n * 128 + c);
    ax = fmaf(di, vs.x, ax);
    ay = fmaf(di, vs.y, ay);
    ax *= di;
    ay *= di;
    // y = (agg + b - rm) * gamma*rsqrt(rv+eps) + beta ; relu
    float sc0 = gamma[c]     * rsqrtf(rv[c]     + EPSV);
    float sc1 = gamma[c + 1] * rsqrtf(rv[c + 1] + EPSV);
    float b0 = fmaf(bsl[c]     - rm[c],     sc0, beta[c]);
    float b1 = fmaf(bsl[c + 1] - rm[c + 1], sc1, beta[c + 1]);
    float y0 = fmaxf(fmaf(ax, sc0, b0), 0.f);
    float y1 = fmaxf(fmaf(ay, sc1, b1), 0.f);
    *(float2*)(out + (size_t)n * 128 + c) = make_float2(y0, y1);
}

// ---------------- global mean pool (batch sorted) ----------------
__global__ __launch_bounds__(128) void k_pool(const float* __restrict__ h,
                                              const int* __restrict__ batch,
                                              float* __restrict__ pooled,
                                              float* __restrict__ cnt) {
    int t = threadIdx.x;  // channel
    const int chunk = (NN + 1023) / 1024;  // 98
    int n0 = blockIdx.x * chunk;
    if (n0 >= NN) return;
    int n1 = n0 + chunk;
    if (n1 > NN) n1 = NN;
    int cur = batch[n0];
    float acc = 0.f;
    int k = 0;
    for (int n = n0; n < n1; ++n) {
        int b = batch[n];
        if (b != cur) {
            atomicAdd(&pooled[(size_t)cur * 128 + t], acc);
            if (t == 0) atomicAdd(&cnt[cur], (float)k);
            acc = 0.f; k = 0; cur = b;
        }
        acc += h[(size_t)n * 128 + t];
        ++k;
    }
    atomicAdd(&pooled[(size_t)cur * 128 + t], acc);
    if (t == 0) atomicAdd(&cnt[cur], (float)k);
}

// ---------------- LSTM (single step, h0=c0=0) + FC ----------------
__global__ __launch_bounds__(128) void k_head(const float* __restrict__ pooled,
                                              const float* __restrict__ cnt,
                                              const float* __restrict__ W_ih,
                                              const float* __restrict__ b_ih,
                                              const float* __restrict__ b_hh,
                                              const float* __restrict__ W_fc,
                                              const float* __restrict__ b_fc,
                                              float* __restrict__ out) {
    __shared__ float pm[128];
    __shared__ float gate[512];
    __shared__ float hn[128];
    int g = blockIdx.x, t = threadIdx.x;
    float cdiv = fmaxf(cnt[g], 1.0f);
    pm[t] = pooled[(size_t)g * 128 + t] / cdiv;
    __syncthreads();
    for (int j = t; j < 512; j += 128) {
        float acc = b_ih[j] + b_hh[j];
        const float* w = W_ih + (size_t)j * 128;
#pragma unroll 8
        for (int k = 0; k < 128; ++k) acc = fmaf(pm[k], w[k], acc);
        gate[j] = acc;
    }
    __syncthreads();
    {
        float gi = gate[t], gg = gate[256 + t], go = gate[384 + t];
        float cc = (1.f / (1.f + expf(-gi))) * tanhf(gg);
        hn[t] = (1.f / (1.f + expf(-go))) * tanhf(cc);
    }
    __syncthreads();
    if (t < 16) {
        float acc = b_fc[t];
        const float* w = W_fc + (size_t)t * 128;
#pragma unroll 8
        for (int k = 0; k < 128; ++k) acc = fmaf(hn[k], w[k], acc);
        out[(size_t)g * 16 + t] = acc;
    }
}

// ---------------- launch ----------------
extern "C" void kernel_launch(void* const* d_in, const int* in_sizes, int n_in,
                              void* d_out, int out_size, void* d_ws, size_t ws_size,
                              hipStream_t stream) {
    const float* x      = (const float*)d_in[0];
    const int*   ei     = (const int*)d_in[1];
    const int*   src    = ei;
    const int*   dst    = ei + EE;
    const int*   batch  = (const int*)d_in[2];
    const float* Ws     = (const float*)d_in[3];
    const float* bs     = (const float*)d_in[4];
    const float* gammas = (const float*)d_in[5];
    const float* betas  = (const float*)d_in[6];
    const float* rms    = (const float*)d_in[7];
    const float* rvs    = (const float*)d_in[8];
    const float* W_ih   = (const float*)d_in[9];
    // d_in[10] = W_hh (unused: h0 = 0)
    const float* b_ih   = (const float*)d_in[11];
    const float* b_hh   = (const float*)d_in[12];
    const float* W_fc   = (const float*)d_in[13];
    const float* b_fc   = (const float*)d_in[14];
    float* out = (float*)d_out;

    char* w = (char*)d_ws;
    float* deg    = (float*)(w + OFF_DEG);   // becomes dinv
    int*   rp     = (int*)(w + OFF_RP);
    int*   cursor = (int*)(w + OFF_CUR);
    int*   ssrc   = (int*)(w + OFF_SRC);
    int*   bsum   = (int*)(w + OFF_BS);
    float* buf0   = (float*)(w + OFF_B0);
    float* buf1   = (float*)(w + OFF_B1);
    float* pooled = (float*)(w + OFF_PL);
    float* cntb   = pooled + (size_t)GG * HH;

    hipMemsetAsync(cursor, 0, (size_t)NN * 4, stream);
    hipMemsetAsync(pooled, 0, ((size_t)GG * HH + GG) * 4, stream);

    k_init_deg<<<(NN + 255) / 256, 256, 0, stream>>>(deg);
    k_count<<<(EE + 255) / 256, 256, 0, stream>>>(dst, deg);
    const int nscan = (NN + 1023) / 1024;  // 98
    k_scan_local<<<nscan, 1024, 0, stream>>>(deg, rp, bsum);
    k_scan_blocks<<<1, 128, 0, stream>>>(bsum, nscan);
    k_scan_add<<<(NN + 255) / 256, 256, 0, stream>>>(rp, bsum);
    k_dinv<<<(NN + 255) / 256, 256, 0, stream>>>(deg);
    k_scatter<<<(EE + 255) / 256, 256, 0, stream>>>(src, dst, rp, cursor, ssrc);

    const float* hin = x;
    for (int l = 0; l < 3; ++l) {
        gemm64<<<(NN + 63) / 64, 256, 0, stream>>>(hin, Ws + (size_t)l * 128 * 128, buf1, NN);
        k_agg<<<(NN + 3) / 4, 256, 0, stream>>>(buf1, rp, ssrc, deg,
                                                bs + l * 128, gammas + l * 128, betas + l * 128,
                                                rms + l * 128, rvs + l * 128, buf0);
        hin = buf0;
    }
    k_pool<<<1024, 128, 0, stream>>>(buf0, batch, pooled, cntb);
    k_head<<<GG, 128, 0, stream>>>(pooled, cntb, W_ih, b_ih, b_hh, W_fc, b_fc, out);
}

// Round 3
// 676.568 us; speedup vs baseline: 19.5437x; 1.2829x over previous
//
#include <hip/hip_runtime.h>
#include <math.h>

// ---------------- problem constants ----------------
constexpr int   NN  = 100000;    // nodes
constexpr int   EE  = 1600000;   // edges
constexpr int   HH  = 128;       // hidden / in_channels
constexpr int   GG  = 128;       // graphs
constexpr float EPSV = 1e-5f;

typedef __attribute__((ext_vector_type(8))) short  short8;
typedef __attribute__((ext_vector_type(4))) float  f32x4;

__device__ __forceinline__ unsigned short f2bf(float f) {
    union { float f; unsigned u; } v; v.f = f;
    unsigned r = v.u + 0x7FFF + ((v.u >> 16) & 1);   // round-to-nearest-even
    return (unsigned short)(r >> 16);
}
__device__ __forceinline__ float bf2f(unsigned short b) {
    union { unsigned u; float f; } v; v.u = ((unsigned)b) << 16;
    return v.f;
}

// ---------------- workspace layout ----------------
constexpr size_t A256(size_t x) { return (x + 255) & ~(size_t)255; }
constexpr size_t OFF_DEG = 0;                                       // N floats (deg -> dinv)
constexpr size_t OFF_RP  = A256(OFF_DEG + (size_t)NN * 4);          // (N+1) ints
constexpr size_t OFF_CUR = A256(OFF_RP  + (size_t)(NN + 1) * 4);    // N ints
constexpr size_t OFF_SRC = A256(OFF_CUR + (size_t)NN * 4);          // E ints sorted src
constexpr size_t OFF_BS  = A256(OFF_SRC + (size_t)EE * 4);          // 512 ints
constexpr size_t OFF_XB  = A256(OFF_BS  + 512 * 4);                 // N*H bf16 (x)
constexpr size_t OFF_HW  = A256(OFF_XB  + (size_t)NN * HH * 2);     // N*H bf16 (h@W)
constexpr size_t OFF_H0  = A256(OFF_HW  + (size_t)NN * HH * 2);     // N*H bf16 (h)
constexpr size_t OFF_PL  = A256(OFF_H0  + (size_t)NN * HH * 2);     // G*H f32 pooled + G f32 cnt

// ---------------- degree / CSR build ----------------
__global__ void k_init_deg(float* deg) {
    int i = blockIdx.x * 256 + threadIdx.x;
    if (i < NN) deg[i] = 1.0f;  // self-loop
}

__global__ void k_count(const int* __restrict__ dst, float* __restrict__ deg) {
    int e = blockIdx.x * 256 + threadIdx.x;
    if (e < EE) atomicAdd(&deg[dst[e]], 1.0f);
}

__global__ __launch_bounds__(1024) void k_scan_local(const float* __restrict__ deg,
                                                     int* __restrict__ row_ptr,
                                                     int* __restrict__ bsum) {
    __shared__ int s[1024];
    int t = threadIdx.x;
    int i = blockIdx.x * 1024 + t;
    int v = 0;
    if (i < NN) v = (int)deg[i] - 1;
    s[t] = v;
    __syncthreads();
    for (int off = 1; off < 1024; off <<= 1) {
        int u = (t >= off) ? s[t - off] : 0;
        __syncthreads();
        s[t] += u;
        __syncthreads();
    }
    if (i < NN) row_ptr[i] = s[t] - v;
    if (t == 1023) bsum[blockIdx.x] = s[1023];
}

__global__ void k_scan_blocks(int* __restrict__ bsum, int nb) {
    __shared__ int s[128];
    int t = threadIdx.x;
    int v = (t < nb) ? bsum[t] : 0;
    s[t] = v;
    __syncthreads();
    for (int off = 1; off < 128; off <<= 1) {
        int u = (t >= off) ? s[t - off] : 0;
        __syncthreads();
        s[t] += u;
        __syncthreads();
    }
    if (t < nb) bsum[t] = s[t] - v;
}

__global__ void k_scan_add(int* __restrict__ row_ptr, const int* __restrict__ bsum) {
    int i = blockIdx.x * 256 + threadIdx.x;
    if (i < NN) row_ptr[i] += bsum[i >> 10];
    if (i == 0) row_ptr[NN] = EE;
}

__global__ void k_dinv(float* __restrict__ deg) {
    int i = blockIdx.x * 256 + threadIdx.x;
    if (i < NN) deg[i] = rsqrtf(deg[i]);
}

__global__ void k_scatter(const int* __restrict__ src, const int* __restrict__ dst,
                          const int* __restrict__ row_ptr, int* __restrict__ cursor,
                          int* __restrict__ ssrc) {
    int e = blockIdx.x * 256 + threadIdx.x;
    if (e < EE) {
        int d = dst[e];
        int p = atomicAdd(&cursor[d], 1);
        ssrc[row_ptr[d] + p] = src[e];
    }
}

// ---------------- x -> bf16 ----------------
__global__ void k_cvt(const float* __restrict__ x, unsigned short* __restrict__ xb) {
    int i = blockIdx.x * 256 + threadIdx.x;
    if (i < NN * (HH / 4)) {
        float4 v = ((const float4*)x)[i];
        ushort4 o;
        o.x = f2bf(v.x); o.y = f2bf(v.y); o.z = f2bf(v.z); o.w = f2bf(v.w);
        ((ushort4*)xb)[i] = o;
    }
}

// ---------------- GEMM: C[N,128] = A[N,128] @ W[128,128], MFMA bf16, split-W ----------------
// 128 rows x 64 cols per block (grid.y = 2 col-blocks). W split hi/lo bf16 in LDS
// (error ~2^-17: weight rounding is systematic and would NOT wash out in pooling).
// A is bf16 single (activation rounding is unbiased -> washes out in mean-pool).
__global__ __launch_bounds__(256) void gemm_mfma(const unsigned short* __restrict__ A,
                                                 const float* __restrict__ W,
                                                 unsigned short* __restrict__ C, int nrows) {
    __shared__ unsigned short smem[2 * 64 * 136];  // WtH | WtL ; reused as Cs[128][68]
    unsigned short* WtH = smem;
    unsigned short* WtL = smem + 64 * 136;

    int t = threadIdx.x;
    int row0 = blockIdx.x * 128;
    int c0   = blockIdx.y * 64;

    // stage W slice transposed + hi/lo split: Wt[c][k], rows padded to 136 elems
    for (int idx = t; idx < 64 * 128; idx += 256) {
        int k = idx >> 6, c = idx & 63;
        float w = W[k * 128 + c0 + c];
        unsigned short hb = f2bf(w);
        unsigned short lb = f2bf(w - bf2f(hb));
        WtH[c * 136 + k] = hb;
        WtL[c * 136 + k] = lb;
    }
    __syncthreads();

    int wv = t >> 6, lane = t & 63, m = lane & 15, q = lane >> 4;
    long rowA = row0 + wv * 32 + m;      // row-tile 0 of this wave
    long rowB = rowA + 16;               // row-tile 1

    f32x4 acc[2][4] = {};
    for (int kc = 0; kc < 4; ++kc) {
        int ko = kc * 32 + q * 8;
        short8 a0 = {}, a1 = {};
        if (rowA < nrows) a0 = *(const short8*)(A + rowA * 128 + ko);
        if (rowB < nrows) a1 = *(const short8*)(A + rowB * 128 + ko);
#pragma unroll
        for (int ct = 0; ct < 4; ++ct) {
            short8 bh = *(const short8*)(WtH + (ct * 16 + m) * 136 + ko);
            short8 bl = *(const short8*)(WtL + (ct * 16 + m) * 136 + ko);
            acc[0][ct] = __builtin_amdgcn_mfma_f32_16x16x32_bf16(a0, bh, acc[0][ct], 0, 0, 0);
            acc[0][ct] = __builtin_amdgcn_mfma_f32_16x16x32_bf16(a0, bl, acc[0][ct], 0, 0, 0);
            acc[1][ct] = __builtin_amdgcn_mfma_f32_16x16x32_bf16(a1, bh, acc[1][ct], 0, 0, 0);
            acc[1][ct] = __builtin_amdgcn_mfma_f32_16x16x32_bf16(a1, bl, acc[1][ct], 0, 0, 0);
        }
    }

    // epilogue: C/D layout is col=lane&15, row=q*4+reg -> transpose via LDS, store coalesced
    __syncthreads();  // done reading Wt
    unsigned short* Cs = smem;  // [128][68]
#pragma unroll
    for (int rt = 0; rt < 2; ++rt)
#pragma unroll
        for (int ct = 0; ct < 4; ++ct)
#pragma unroll
            for (int r = 0; r < 4; ++r) {
                int rl = wv * 32 + rt * 16 + q * 4 + r;
                Cs[rl * 68 + ct * 16 + m] = f2bf(acc[rt][ct][r]);
            }
    __syncthreads();
    for (int idx = t; idx < 128 * 16; idx += 256) {
        int row = idx >> 4, ch = idx & 15;
        long grow = row0 + row;
        if (grow < nrows)
            *(ushort4*)(C + grow * 128 + c0 + ch * 4) = *(const ushort4*)(Cs + row * 68 + ch * 4);
    }
}

// ---------------- aggregate + bias + BN + ReLU (bf16 gather, fp32 accum) ----------------
// one wave per node; 2 edges/wave (half = lane>>5), 4 channels/lane (ushort4 = 8B),
// 8-step pipeline = 16 edges per iteration; __shfl_xor(32) combines the halves.
__global__ __launch_bounds__(256) void k_agg(const unsigned short* __restrict__ hw,
                                             const int* __restrict__ rp,
                                             const int* __restrict__ ssrc,
                                             const float* __restrict__ dinv,
                                             const float* __restrict__ bsl,
                                             const float* __restrict__ gamma,
                                             const float* __restrict__ beta,
                                             const float* __restrict__ rm,
                                             const float* __restrict__ rv,
                                             unsigned short* __restrict__ out) {
    int lane = threadIdx.x & 63;
    int half = lane >> 5;
    int c    = (lane & 31) * 4;
    int n = blockIdx.x * 4 + (threadIdx.x >> 6);
    if (n >= NN) return;
    int beg = rp[n], end = rp[n + 1];
    float a0 = 0.f, a1 = 0.f, a2 = 0.f, a3 = 0.f;

    for (int e = beg; e < end; e += 16) {
        float ds8[8];
        const unsigned short* p8[8];
#pragma unroll
        for (int i = 0; i < 8; ++i) {
            int ei = e + 2 * i + half;
            int si = (ei < end) ? ei : (end - 1);
            int s  = ssrc[si];
            float mk = (ei < end) ? 1.0f : 0.0f;
            ds8[i] = mk * dinv[s];
            p8[i]  = hw + (size_t)s * 128 + c;
        }
#pragma unroll
        for (int i = 0; i < 8; ++i) {
            ushort4 v = *(const ushort4*)p8[i];
            a0 = fmaf(ds8[i], bf2f(v.x), a0);
            a1 = fmaf(ds8[i], bf2f(v.y), a1);
            a2 = fmaf(ds8[i], bf2f(v.z), a2);
            a3 = fmaf(ds8[i], bf2f(v.w), a3);
        }
    }
    // combine the two halves (wave-uniform control flow here)
    a0 += __shfl_xor(a0, 32);
    a1 += __shfl_xor(a1, 32);
    a2 += __shfl_xor(a2, 32);
    a3 += __shfl_xor(a3, 32);

    if (half == 0) {
        float di = dinv[n];
        ushort4 sv = *(const ushort4*)(hw + (size_t)n * 128 + c);
        a0 = fmaf(di, bf2f(sv.x), a0);
        a1 = fmaf(di, bf2f(sv.y), a1);
        a2 = fmaf(di, bf2f(sv.z), a2);
        a3 = fmaf(di, bf2f(sv.w), a3);
        a0 *= di; a1 *= di; a2 *= di; a3 *= di;
        float4 g  = *(const float4*)(gamma + c);
        float4 bt = *(const float4*)(beta + c);
        float4 rmv = *(const float4*)(rm + c);
        float4 rvv = *(const float4*)(rv + c);
        float4 bb = *(const float4*)(bsl + c);
        float s0 = g.x * rsqrtf(rvv.x + EPSV);
        float s1 = g.y * rsqrtf(rvv.y + EPSV);
        float s2 = g.z * rsqrtf(rvv.z + EPSV);
        float s3 = g.w * rsqrtf(rvv.w + EPSV);
        float y0 = fmaxf(fmaf(a0, s0, fmaf(bb.x - rmv.x, s0, bt.x)), 0.f);
        float y1 = fmaxf(fmaf(a1, s1, fmaf(bb.y - rmv.y, s1, bt.y)), 0.f);
        float y2 = fmaxf(fmaf(a2, s2, fmaf(bb.z - rmv.z, s2, bt.z)), 0.f);
        float y3 = fmaxf(fmaf(a3, s3, fmaf(bb.w - rmv.w, s3, bt.w)), 0.f);
        ushort4 o;
        o.x = f2bf(y0); o.y = f2bf(y1); o.z = f2bf(y2); o.w = f2bf(y3);
        *(ushort4*)(out + (size_t)n * 128 + c) = o;
    }
}

// ---------------- global mean pool (batch sorted, bf16 input) ----------------
__global__ __launch_bounds__(128) void k_pool(const unsigned short* __restrict__ h,
                                              const int* __restrict__ batch,
                                              float* __restrict__ pooled,
                                              float* __restrict__ cnt) {
    int t = threadIdx.x;
    const int chunk = (NN + 1023) / 1024;
    int n0 = blockIdx.x * chunk;
    if (n0 >= NN) return;
    int n1 = n0 + chunk;
    if (n1 > NN) n1 = NN;
    int cur = batch[n0];
    float acc = 0.f;
    int k = 0;
    for (int n = n0; n < n1; ++n) {
        int b = batch[n];
        if (b != cur) {
            atomicAdd(&pooled[(size_t)cur * 128 + t], acc);
            if (t == 0) atomicAdd(&cnt[cur], (float)k);
            acc = 0.f; k = 0; cur = b;
        }
        acc += bf2f(h[(size_t)n * 128 + t]);
        ++k;
    }
    atomicAdd(&pooled[(size_t)cur * 128 + t], acc);
    if (t == 0) atomicAdd(&cnt[cur], (float)k);
}

// ---------------- LSTM (single step, h0=c0=0) + FC ----------------
__global__ __launch_bounds__(128) void k_head(const float* __restrict__ pooled,
                                              const float* __restrict__ cnt,
                                              const float* __restrict__ W_ih,
                                              const float* __restrict__ b_ih,
                                              const float* __restrict__ b_hh,
                                              const float* __restrict__ W_fc,
                                              const float* __restrict__ b_fc,
                                              float* __restrict__ out) {
    __shared__ float pm[128];
    __shared__ float gate[512];
    __shared__ float hn[128];
    int g = blockIdx.x, t = threadIdx.x;
    float cdiv = fmaxf(cnt[g], 1.0f);
    pm[t] = pooled[(size_t)g * 128 + t] / cdiv;
    __syncthreads();
    for (int j = t; j < 512; j += 128) {
        float acc = b_ih[j] + b_hh[j];
        const float* w = W_ih + (size_t)j * 128;
#pragma unroll 8
        for (int k = 0; k < 128; ++k) acc = fmaf(pm[k], w[k], acc);
        gate[j] = acc;
    }
    __syncthreads();
    {
        float gi = gate[t], gg = gate[256 + t], go = gate[384 + t];
        float cc = (1.f / (1.f + expf(-gi))) * tanhf(gg);
        hn[t] = (1.f / (1.f + expf(-go))) * tanhf(cc);
    }
    __syncthreads();
    if (t < 16) {
        float acc = b_fc[t];
        const float* w = W_fc + (size_t)t * 128;
#pragma unroll 8
        for (int k = 0; k < 128; ++k) acc = fmaf(hn[k], w[k], acc);
        out[(size_t)g * 16 + t] = acc;
    }
}

// ---------------- launch ----------------
extern "C" void kernel_launch(void* const* d_in, const int* in_sizes, int n_in,
                              void* d_out, int out_size, void* d_ws, size_t ws_size,
                              hipStream_t stream) {
    const float* x      = (const float*)d_in[0];
    const int*   ei     = (const int*)d_in[1];
    const int*   src    = ei;
    const int*   dst    = ei + EE;
    const int*   batch  = (const int*)d_in[2];
    const float* Ws     = (const float*)d_in[3];
    const float* bs     = (const float*)d_in[4];
    const float* gammas = (const float*)d_in[5];
    const float* betas  = (const float*)d_in[6];
    const float* rms    = (const float*)d_in[7];
    const float* rvs    = (const float*)d_in[8];
    const float* W_ih   = (const float*)d_in[9];
    // d_in[10] = W_hh (unused: h0 = 0)
    const float* b_ih   = (const float*)d_in[11];
    const float* b_hh   = (const float*)d_in[12];
    const float* W_fc   = (const float*)d_in[13];
    const float* b_fc   = (const float*)d_in[14];
    float* out = (float*)d_out;

    char* w = (char*)d_ws;
    float*          deg    = (float*)(w + OFF_DEG);
    int*            rp     = (int*)(w + OFF_RP);
    int*            cursor = (int*)(w + OFF_CUR);
    int*            ssrc   = (int*)(w + OFF_SRC);
    int*            bsum   = (int*)(w + OFF_BS);
    unsigned short* xb     = (unsigned short*)(w + OFF_XB);
    unsigned short* hwb    = (unsigned short*)(w + OFF_HW);
    unsigned short* h0     = (unsigned short*)(w + OFF_H0);
    float*          pooled = (float*)(w + OFF_PL);
    float*          cntb   = pooled + (size_t)GG * HH;

    hipMemsetAsync(cursor, 0, (size_t)NN * 4, stream);
    hipMemsetAsync(pooled, 0, ((size_t)GG * HH + GG) * 4, stream);

    k_init_deg<<<(NN + 255) / 256, 256, 0, stream>>>(deg);
    k_count<<<(EE + 255) / 256, 256, 0, stream>>>(dst, deg);
    const int nscan = (NN + 1023) / 1024;
    k_scan_local<<<nscan, 1024, 0, stream>>>(deg, rp, bsum);
    k_scan_blocks<<<1, 128, 0, stream>>>(bsum, nscan);
    k_scan_add<<<(NN + 255) / 256, 256, 0, stream>>>(rp, bsum);
    k_dinv<<<(NN + 255) / 256, 256, 0, stream>>>(deg);
    k_scatter<<<(EE + 255) / 256, 256, 0, stream>>>(src, dst, rp, cursor, ssrc);
    k_cvt<<<(NN * 32 + 255) / 256, 256, 0, stream>>>(x, xb);

    const unsigned short* hin = xb;
    dim3 ggrid((NN + 127) / 128, 2);
    for (int l = 0; l < 3; ++l) {
        gemm_mfma<<<ggrid, 256, 0, stream>>>(hin, Ws + (size_t)l * 128 * 128, hwb, NN);
        k_agg<<<(NN + 3) / 4, 256, 0, stream>>>(hwb, rp, ssrc, deg,
                                                bs + l * 128, gammas + l * 128, betas + l * 128,
                                                rms + l * 128, rvs + l * 128, h0);
        hin = h0;
    }
    k_pool<<<1024, 128, 0, stream>>>(h0, batch, pooled, cntb);
    k_head<<<GG, 128, 0, stream>>>(pooled, cntb, W_ih, b_ih, b_hh, W_fc, b_fc, out);
}

// Round 4
// 621.268 us; speedup vs baseline: 21.2833x; 1.0890x over previous
//
#include <hip/hip_runtime.h>
#include <math.h>

// ---------------- problem constants ----------------
constexpr int   NN  = 100000;    // nodes
constexpr int   EE  = 1600000;   // edges
constexpr int   HH  = 128;       // hidden / in_channels
constexpr int   GG  = 128;       // graphs
constexpr float EPSV = 1e-5f;
constexpr int   NSH = 8;         // XCD shards (blockIdx&7 -> XCD heuristic)
constexpr int   SHN = NN / NSH;  // 12500 nodes per shard

typedef __attribute__((ext_vector_type(8))) short  short8;
typedef __attribute__((ext_vector_type(4))) float  f32x4;

__device__ __forceinline__ unsigned short f2bf(float f) {
    union { float f; unsigned u; } v; v.f = f;
    unsigned r = v.u + 0x7FFF + ((v.u >> 16) & 1);   // round-to-nearest-even
    return (unsigned short)(r >> 16);
}
__device__ __forceinline__ float bf2f(unsigned short b) {
    union { unsigned u; float f; } v; v.u = ((unsigned)b) << 16;
    return v.f;
}

// ---------------- workspace layout ----------------
constexpr size_t A256(size_t x) { return (x + 255) & ~(size_t)255; }
constexpr size_t OFF_DEG = 0;                                       // N ints (edge counts)
constexpr size_t OFF_DNV = A256(OFF_DEG + (size_t)NN * 4);          // N floats dinv
constexpr size_t OFF_RP  = A256(OFF_DNV + (size_t)NN * 4);          // (N+1) ints
constexpr size_t OFF_CUR = A256(OFF_RP  + (size_t)(NN + 1) * 4);    // N ints (running cursor)
constexpr size_t OFF_SRC = A256(OFF_CUR + (size_t)NN * 4);          // E ints sorted src
constexpr size_t OFF_BS  = A256(OFF_SRC + (size_t)EE * 4);          // 512 ints
constexpr size_t OFF_XB  = A256(OFF_BS  + 512 * 4);                 // N*H bf16 (x)
constexpr size_t OFF_HW  = A256(OFF_XB  + (size_t)NN * HH * 2);     // N*H bf16 (h@W)
constexpr size_t OFF_H0  = A256(OFF_HW  + (size_t)NN * HH * 2);     // N*H bf16 (h)
constexpr size_t OFF_PL  = A256(OFF_H0  + (size_t)NN * HH * 2);     // G*H f32 pooled + G f32 cnt

// ---------------- degree count (XCD-sharded atomics) ----------------
// blockIdx&7 selects a 12500-node dst range; with round-robin block->XCD
// dispatch each deg shard (50 KB) stays resident in ONE XCD's L2 -> no
// cross-XCD atomic line ping-pong. All 8 siblings stream the same dst
// chunks -> L3 serves 7/8 of the reads.
__global__ __launch_bounds__(256) void k_count(const int* __restrict__ dst,
                                               int* __restrict__ deg) {
    int shard = blockIdx.x & 7;
    int chunk = blockIdx.x >> 3;            // 0..255
    int lo = SHN * shard, hi = lo + SHN;
    const int4* d4 = (const int4*)dst;
    const int nvec = EE / 4;
    for (int i = chunk * 256 + threadIdx.x; i < nvec; i += 256 * 256) {
        int4 d = d4[i];
        if (d.x >= lo && d.x < hi) atomicAdd(&deg[d.x], 1);
        if (d.y >= lo && d.y < hi) atomicAdd(&deg[d.y], 1);
        if (d.z >= lo && d.z < hi) atomicAdd(&deg[d.z], 1);
        if (d.w >= lo && d.w < hi) atomicAdd(&deg[d.w], 1);
    }
}

__global__ __launch_bounds__(1024) void k_scan_local(const int* __restrict__ deg,
                                                     int* __restrict__ row_ptr,
                                                     int* __restrict__ bsum) {
    __shared__ int s[1024];
    int t = threadIdx.x;
    int i = blockIdx.x * 1024 + t;
    int v = (i < NN) ? deg[i] : 0;
    s[t] = v;
    __syncthreads();
    for (int off = 1; off < 1024; off <<= 1) {
        int u = (t >= off) ? s[t - off] : 0;
        __syncthreads();
        s[t] += u;
        __syncthreads();
    }
    if (i < NN) row_ptr[i] = s[t] - v;
    if (t == 1023) bsum[blockIdx.x] = s[1023];
}

__global__ void k_scan_blocks(int* __restrict__ bsum, int nb) {
    __shared__ int s[128];
    int t = threadIdx.x;
    int v = (t < nb) ? bsum[t] : 0;
    s[t] = v;
    __syncthreads();
    for (int off = 1; off < 128; off <<= 1) {
        int u = (t >= off) ? s[t - off] : 0;
        __syncthreads();
        s[t] += u;
        __syncthreads();
    }
    if (t < nb) bsum[t] = s[t] - v;
}

// final row_ptr; also pre-fill the scatter cursor (saves a memset + a read)
__global__ void k_scan_add(int* __restrict__ row_ptr, const int* __restrict__ bsum,
                           int* __restrict__ cursor) {
    int i = blockIdx.x * 256 + threadIdx.x;
    if (i < NN) {
        int v = row_ptr[i] + bsum[i >> 10];
        row_ptr[i] = v;
        cursor[i] = v;
    }
    if (i == 0) row_ptr[NN] = EE;
}

__global__ void k_dinv(const int* __restrict__ deg, float* __restrict__ dinv) {
    int i = blockIdx.x * 256 + threadIdx.x;
    if (i < NN) dinv[i] = rsqrtf((float)(deg[i] + 1));  // +1 self-loop
}

// ---------------- scatter (XCD-sharded) ----------------
// R3 lesson: unsharded random 4B writes gave 107 MB HBM write for a 6.4 MB
// array (one full line writeback per edge). Sharding makes each ssrc line
// written entirely from one XCD's L2 -> written back once.
__global__ __launch_bounds__(256) void k_scatter(const int* __restrict__ src,
                                                 const int* __restrict__ dst,
                                                 int* __restrict__ cursor,
                                                 int* __restrict__ ssrc) {
    int shard = blockIdx.x & 7;
    int chunk = blockIdx.x >> 3;
    int lo = SHN * shard, hi = lo + SHN;
    const int4* s4 = (const int4*)src;
    const int4* d4 = (const int4*)dst;
    const int nvec = EE / 4;
    for (int i = chunk * 256 + threadIdx.x; i < nvec; i += 256 * 256) {
        int4 d = d4[i];
        int4 s = s4[i];
        if (d.x >= lo && d.x < hi) ssrc[atomicAdd(&cursor[d.x], 1)] = s.x;
        if (d.y >= lo && d.y < hi) ssrc[atomicAdd(&cursor[d.y], 1)] = s.y;
        if (d.z >= lo && d.z < hi) ssrc[atomicAdd(&cursor[d.z], 1)] = s.z;
        if (d.w >= lo && d.w < hi) ssrc[atomicAdd(&cursor[d.w], 1)] = s.w;
    }
}

// ---------------- x -> bf16 ----------------
__global__ void k_cvt(const float* __restrict__ x, unsigned short* __restrict__ xb) {
    int i = blockIdx.x * 256 + threadIdx.x;
    if (i < NN * (HH / 4)) {
        float4 v = ((const float4*)x)[i];
        ushort4 o;
        o.x = f2bf(v.x); o.y = f2bf(v.y); o.z = f2bf(v.z); o.w = f2bf(v.w);
        ((ushort4*)xb)[i] = o;
    }
}

// ---------------- GEMM: C[N,128] = A[N,128] @ W[128,128], MFMA bf16, split-W ----------------
__global__ __launch_bounds__(256) void gemm_mfma(const unsigned short* __restrict__ A,
                                                 const float* __restrict__ W,
                                                 unsigned short* __restrict__ C, int nrows) {
    __shared__ unsigned short smem[2 * 64 * 136];  // WtH | WtL ; reused as Cs[128][68]
    unsigned short* WtH = smem;
    unsigned short* WtL = smem + 64 * 136;

    int t = threadIdx.x;
    int row0 = blockIdx.x * 128;
    int c0   = blockIdx.y * 64;

    for (int idx = t; idx < 64 * 128; idx += 256) {
        int k = idx >> 6, c = idx & 63;
        float w = W[k * 128 + c0 + c];
        unsigned short hb = f2bf(w);
        unsigned short lb = f2bf(w - bf2f(hb));
        WtH[c * 136 + k] = hb;
        WtL[c * 136 + k] = lb;
    }
    __syncthreads();

    int wv = t >> 6, lane = t & 63, m = lane & 15, q = lane >> 4;
    long rowA = row0 + wv * 32 + m;
    long rowB = rowA + 16;

    f32x4 acc[2][4] = {};
    for (int kc = 0; kc < 4; ++kc) {
        int ko = kc * 32 + q * 8;
        short8 a0 = {}, a1 = {};
        if (rowA < nrows) a0 = *(const short8*)(A + rowA * 128 + ko);
        if (rowB < nrows) a1 = *(const short8*)(A + rowB * 128 + ko);
#pragma unroll
        for (int ct = 0; ct < 4; ++ct) {
            short8 bh = *(const short8*)(WtH + (ct * 16 + m) * 136 + ko);
            short8 bl = *(const short8*)(WtL + (ct * 16 + m) * 136 + ko);
            acc[0][ct] = __builtin_amdgcn_mfma_f32_16x16x32_bf16(a0, bh, acc[0][ct], 0, 0, 0);
            acc[0][ct] = __builtin_amdgcn_mfma_f32_16x16x32_bf16(a0, bl, acc[0][ct], 0, 0, 0);
            acc[1][ct] = __builtin_amdgcn_mfma_f32_16x16x32_bf16(a1, bh, acc[1][ct], 0, 0, 0);
            acc[1][ct] = __builtin_amdgcn_mfma_f32_16x16x32_bf16(a1, bl, acc[1][ct], 0, 0, 0);
        }
    }

    __syncthreads();
    unsigned short* Cs = smem;  // [128][68]
#pragma unroll
    for (int rt = 0; rt < 2; ++rt)
#pragma unroll
        for (int ct = 0; ct < 4; ++ct)
#pragma unroll
            for (int r = 0; r < 4; ++r) {
                int rl = wv * 32 + rt * 16 + q * 4 + r;
                Cs[rl * 68 + ct * 16 + m] = f2bf(acc[rt][ct][r]);
            }
    __syncthreads();
    for (int idx = t; idx < 128 * 16; idx += 256) {
        int row = idx >> 4, ch = idx & 15;
        long grow = row0 + row;
        if (grow < nrows)
            *(ushort4*)(C + grow * 128 + c0 + ch * 4) = *(const ushort4*)(Cs + row * 68 + ch * 4);
    }
}

// ---------------- aggregate + bias + BN + ReLU (bf16 gather, fp32 accum) ----------------
__global__ __launch_bounds__(256) void k_agg(const unsigned short* __restrict__ hw,
                                             const int* __restrict__ rp,
                                             const int* __restrict__ ssrc,
                                             const float* __restrict__ dinv,
                                             const float* __restrict__ bsl,
                                             const float* __restrict__ gamma,
                                             const float* __restrict__ beta,
                                             const float* __restrict__ rm,
                                             const float* __restrict__ rv,
                                             unsigned short* __restrict__ out) {
    int lane = threadIdx.x & 63;
    int half = lane >> 5;
    int c    = (lane & 31) * 4;
    int n = blockIdx.x * 4 + (threadIdx.x >> 6);
    if (n >= NN) return;
    int beg = rp[n], end = rp[n + 1];
    float a0 = 0.f, a1 = 0.f, a2 = 0.f, a3 = 0.f;

    for (int e = beg; e < end; e += 16) {
        float ds8[8];
        const unsigned short* p8[8];
#pragma unroll
        for (int i = 0; i < 8; ++i) {
            int ei = e + 2 * i + half;
            int si = (ei < end) ? ei : (end - 1);
            int s  = ssrc[si];
            float mk = (ei < end) ? 1.0f : 0.0f;
            ds8[i] = mk * dinv[s];
            p8[i]  = hw + (size_t)s * 128 + c;
        }
#pragma unroll
        for (int i = 0; i < 8; ++i) {
            ushort4 v = *(const ushort4*)p8[i];
            a0 = fmaf(ds8[i], bf2f(v.x), a0);
            a1 = fmaf(ds8[i], bf2f(v.y), a1);
            a2 = fmaf(ds8[i], bf2f(v.z), a2);
            a3 = fmaf(ds8[i], bf2f(v.w), a3);
        }
    }
    a0 += __shfl_xor(a0, 32);
    a1 += __shfl_xor(a1, 32);
    a2 += __shfl_xor(a2, 32);
    a3 += __shfl_xor(a3, 32);

    if (half == 0) {
        float di = dinv[n];
        ushort4 sv = *(const ushort4*)(hw + (size_t)n * 128 + c);
        a0 = fmaf(di, bf2f(sv.x), a0);
        a1 = fmaf(di, bf2f(sv.y), a1);
        a2 = fmaf(di, bf2f(sv.z), a2);
        a3 = fmaf(di, bf2f(sv.w), a3);
        a0 *= di; a1 *= di; a2 *= di; a3 *= di;
        float4 g  = *(const float4*)(gamma + c);
        float4 bt = *(const float4*)(beta + c);
        float4 rmv = *(const float4*)(rm + c);
        float4 rvv = *(const float4*)(rv + c);
        float4 bb = *(const float4*)(bsl + c);
        float s0 = g.x * rsqrtf(rvv.x + EPSV);
        float s1 = g.y * rsqrtf(rvv.y + EPSV);
        float s2 = g.z * rsqrtf(rvv.z + EPSV);
        float s3 = g.w * rsqrtf(rvv.w + EPSV);
        float y0 = fmaxf(fmaf(a0, s0, fmaf(bb.x - rmv.x, s0, bt.x)), 0.f);
        float y1 = fmaxf(fmaf(a1, s1, fmaf(bb.y - rmv.y, s1, bt.y)), 0.f);
        float y2 = fmaxf(fmaf(a2, s2, fmaf(bb.z - rmv.z, s2, bt.z)), 0.f);
        float y3 = fmaxf(fmaf(a3, s3, fmaf(bb.w - rmv.w, s3, bt.w)), 0.f);
        ushort4 o;
        o.x = f2bf(y0); o.y = f2bf(y1); o.z = f2bf(y2); o.w = f2bf(y3);
        *(ushort4*)(out + (size_t)n * 128 + c) = o;
    }
}

// ---------------- global mean pool (batch sorted, bf16 input) ----------------
__global__ __launch_bounds__(128) void k_pool(const unsigned short* __restrict__ h,
                                              const int* __restrict__ batch,
                                              float* __restrict__ pooled,
                                              float* __restrict__ cnt) {
    int t = threadIdx.x;
    const int chunk = (NN + 1023) / 1024;
    int n0 = blockIdx.x * chunk;
    if (n0 >= NN) return;
    int n1 = n0 + chunk;
    if (n1 > NN) n1 = NN;
    int cur = batch[n0];
    float acc = 0.f;
    int k = 0;
    for (int n = n0; n < n1; ++n) {
        int b = batch[n];
        if (b != cur) {
            atomicAdd(&pooled[(size_t)cur * 128 + t], acc);
            if (t == 0) atomicAdd(&cnt[cur], (float)k);
            acc = 0.f; k = 0; cur = b;
        }
        acc += bf2f(h[(size_t)n * 128 + t]);
        ++k;
    }
    atomicAdd(&pooled[(size_t)cur * 128 + t], acc);
    if (t == 0) atomicAdd(&cnt[cur], (float)k);
}

// ---------------- LSTM (single step, h0=c0=0) + FC ----------------
__global__ __launch_bounds__(128) void k_head(const float* __restrict__ pooled,
                                              const float* __restrict__ cnt,
                                              const float* __restrict__ W_ih,
                                              const float* __restrict__ b_ih,
                                              const float* __restrict__ b_hh,
                                              const float* __restrict__ W_fc,
                                              const float* __restrict__ b_fc,
                                              float* __restrict__ out) {
    __shared__ float pm[128];
    __shared__ float gate[512];
    __shared__ float hn[128];
    int g = blockIdx.x, t = threadIdx.x;
    float cdiv = fmaxf(cnt[g], 1.0f);
    pm[t] = pooled[(size_t)g * 128 + t] / cdiv;
    __syncthreads();
    for (int j = t; j < 512; j += 128) {
        float acc = b_ih[j] + b_hh[j];
        const float* w = W_ih + (size_t)j * 128;
#pragma unroll 8
        for (int k = 0; k < 128; ++k) acc = fmaf(pm[k], w[k], acc);
        gate[j] = acc;
    }
    __syncthreads();
    {
        float gi = gate[t], gg = gate[256 + t], go = gate[384 + t];
        float cc = (1.f / (1.f + expf(-gi))) * tanhf(gg);
        hn[t] = (1.f / (1.f + expf(-go))) * tanhf(cc);
    }
    __syncthreads();
    if (t < 16) {
        float acc = b_fc[t];
        const float* w = W_fc + (size_t)t * 128;
#pragma unroll 8
        for (int k = 0; k < 128; ++k) acc = fmaf(hn[k], w[k], acc);
        out[(size_t)g * 16 + t] = acc;
    }
}

// ---------------- launch ----------------
extern "C" void kernel_launch(void* const* d_in, const int* in_sizes, int n_in,
                              void* d_out, int out_size, void* d_ws, size_t ws_size,
                              hipStream_t stream) {
    const float* x      = (const float*)d_in[0];
    const int*   ei     = (const int*)d_in[1];
    const int*   src    = ei;
    const int*   dst    = ei + EE;
    const int*   batch  = (const int*)d_in[2];
    const float* Ws     = (const float*)d_in[3];
    const float* bs     = (const float*)d_in[4];
    const float* gammas = (const float*)d_in[5];
    const float* betas  = (const float*)d_in[6];
    const float* rms    = (const float*)d_in[7];
    const float* rvs    = (const float*)d_in[8];
    const float* W_ih   = (const float*)d_in[9];
    // d_in[10] = W_hh (unused: h0 = 0)
    const float* b_ih   = (const float*)d_in[11];
    const float* b_hh   = (const float*)d_in[12];
    const float* W_fc   = (const float*)d_in[13];
    const float* b_fc   = (const float*)d_in[14];
    float* out = (float*)d_out;

    char* w = (char*)d_ws;
    int*            deg    = (int*)(w + OFF_DEG);
    float*          dinv   = (float*)(w + OFF_DNV);
    int*            rp     = (int*)(w + OFF_RP);
    int*            cursor = (int*)(w + OFF_CUR);
    int*            ssrc   = (int*)(w + OFF_SRC);
    int*            bsum   = (int*)(w + OFF_BS);
    unsigned short* xb     = (unsigned short*)(w + OFF_XB);
    unsigned short* hwb    = (unsigned short*)(w + OFF_HW);
    unsigned short* h0     = (unsigned short*)(w + OFF_H0);
    float*          pooled = (float*)(w + OFF_PL);
    float*          cntb   = pooled + (size_t)GG * HH;

    hipMemsetAsync(deg, 0, (size_t)NN * 4, stream);
    hipMemsetAsync(pooled, 0, ((size_t)GG * HH + GG) * 4, stream);

    k_count<<<2048, 256, 0, stream>>>(dst, deg);
    const int nscan = (NN + 1023) / 1024;
    k_scan_local<<<nscan, 1024, 0, stream>>>(deg, rp, bsum);
    k_scan_blocks<<<1, 128, 0, stream>>>(bsum, nscan);
    k_scan_add<<<(NN + 255) / 256, 256, 0, stream>>>(rp, bsum, cursor);
    k_dinv<<<(NN + 255) / 256, 256, 0, stream>>>(deg, dinv);
    k_scatter<<<2048, 256, 0, stream>>>(src, dst, cursor, ssrc);
    k_cvt<<<(NN * 32 + 255) / 256, 256, 0, stream>>>(x, xb);

    const unsigned short* hin = xb;
    dim3 ggrid((NN + 127) / 128, 2);
    for (int l = 0; l < 3; ++l) {
        gemm_mfma<<<ggrid, 256, 0, stream>>>(hin, Ws + (size_t)l * 128 * 128, hwb, NN);
        k_agg<<<(NN + 3) / 4, 256, 0, stream>>>(hwb, rp, ssrc, dinv,
                                                bs + l * 128, gammas + l * 128, betas + l * 128,
                                                rms + l * 128, rvs + l * 128, h0);
        hin = h0;
    }
    k_pool<<<1024, 128, 0, stream>>>(h0, batch, pooled, cntb);
    k_head<<<GG, 128, 0, stream>>>(pooled, cntb, W_ih, b_ih, b_hh, W_fc, b_fc, out);
}

// Round 5
// 582.767 us; speedup vs baseline: 22.6894x; 1.0661x over previous
//
#include <hip/hip_runtime.h>
#include <math.h>

// ---------------- problem constants ----------------
constexpr int   NN  = 100000;    // nodes
constexpr int   EE  = 1600000;   // edges
constexpr int   HH  = 128;       // hidden / in_channels
constexpr int   GG  = 128;       // graphs
constexpr float EPSV = 1e-5f;
constexpr int   NSH = 8;         // XCD shards (blockIdx&7 -> XCD heuristic)
constexpr int   SHN = NN / NSH;  // 12500 nodes per shard

typedef __attribute__((ext_vector_type(8))) short  short8;
typedef __attribute__((ext_vector_type(4))) float  f32x4;
typedef __attribute__((ext_vector_type(2))) float  v2f;

__device__ __forceinline__ unsigned short f2bf(float f) {
    union { float f; unsigned u; } v; v.f = f;
    unsigned r = v.u + 0x7FFF + ((v.u >> 16) & 1);   // round-to-nearest-even
    return (unsigned short)(r >> 16);
}
__device__ __forceinline__ float bf2f(unsigned short b) {
    union { unsigned u; float f; } v; v.u = ((unsigned)b) << 16;
    return v.f;
}

// ---------------- workspace layout ----------------
constexpr size_t A256(size_t x) { return (x + 255) & ~(size_t)255; }
constexpr size_t OFF_DEG = 0;                                       // N ints (edge counts)
constexpr size_t OFF_DNV = A256(OFF_DEG + (size_t)NN * 4);          // N floats dinv
constexpr size_t OFF_RP  = A256(OFF_DNV + (size_t)NN * 4);          // (N+1) ints
constexpr size_t OFF_CUR = A256(OFF_RP  + (size_t)(NN + 1) * 4);    // N ints (running cursor)
constexpr size_t OFF_SRC = A256(OFF_CUR + (size_t)NN * 4);          // E ints sorted src
constexpr size_t OFF_BS  = A256(OFF_SRC + (size_t)EE * 4);          // 512 ints
constexpr size_t OFF_XB  = A256(OFF_BS  + 512 * 4);                 // N*H bf16 (x)
constexpr size_t OFF_HW  = A256(OFF_XB  + (size_t)NN * HH * 2);     // N*H bf16 (h@W)
constexpr size_t OFF_H0  = A256(OFF_HW  + (size_t)NN * HH * 2);     // N*H bf16 (h)
constexpr size_t OFF_PL  = A256(OFF_H0  + (size_t)NN * HH * 2);     // G*H f32 pooled + G f32 cnt

// ---------------- degree count (XCD-sharded atomics) ----------------
__global__ __launch_bounds__(256) void k_count(const int* __restrict__ dst,
                                               int* __restrict__ deg) {
    int shard = blockIdx.x & 7;
    int chunk = blockIdx.x >> 3;            // 0..255
    int lo = SHN * shard, hi = lo + SHN;
    const int4* d4 = (const int4*)dst;
    const int nvec = EE / 4;
    for (int i = chunk * 256 + threadIdx.x; i < nvec; i += 256 * 256) {
        int4 d = d4[i];
        if (d.x >= lo && d.x < hi) atomicAdd(&deg[d.x], 1);
        if (d.y >= lo && d.y < hi) atomicAdd(&deg[d.y], 1);
        if (d.z >= lo && d.z < hi) atomicAdd(&deg[d.z], 1);
        if (d.w >= lo && d.w < hi) atomicAdd(&deg[d.w], 1);
    }
}

__global__ __launch_bounds__(1024) void k_scan_local(const int* __restrict__ deg,
                                                     int* __restrict__ row_ptr,
                                                     int* __restrict__ bsum) {
    __shared__ int s[1024];
    int t = threadIdx.x;
    int i = blockIdx.x * 1024 + t;
    int v = (i < NN) ? deg[i] : 0;
    s[t] = v;
    __syncthreads();
    for (int off = 1; off < 1024; off <<= 1) {
        int u = (t >= off) ? s[t - off] : 0;
        __syncthreads();
        s[t] += u;
        __syncthreads();
    }
    if (i < NN) row_ptr[i] = s[t] - v;
    if (t == 1023) bsum[blockIdx.x] = s[1023];
}

__global__ void k_scan_blocks(int* __restrict__ bsum, int nb) {
    __shared__ int s[128];
    int t = threadIdx.x;
    int v = (t < nb) ? bsum[t] : 0;
    s[t] = v;
    __syncthreads();
    for (int off = 1; off < 128; off <<= 1) {
        int u = (t >= off) ? s[t - off] : 0;
        __syncthreads();
        s[t] += u;
        __syncthreads();
    }
    if (t < nb) bsum[t] = s[t] - v;
}

__global__ void k_scan_add(int* __restrict__ row_ptr, const int* __restrict__ bsum,
                           int* __restrict__ cursor) {
    int i = blockIdx.x * 256 + threadIdx.x;
    if (i < NN) {
        int v = row_ptr[i] + bsum[i >> 10];
        row_ptr[i] = v;
        cursor[i] = v;
    }
    if (i == 0) row_ptr[NN] = EE;
}

__global__ void k_dinv(const int* __restrict__ deg, float* __restrict__ dinv) {
    int i = blockIdx.x * 256 + threadIdx.x;
    if (i < NN) dinv[i] = rsqrtf((float)(deg[i] + 1));  // +1 self-loop
}

// ---------------- scatter (XCD-sharded) ----------------
__global__ __launch_bounds__(256) void k_scatter(const int* __restrict__ src,
                                                 const int* __restrict__ dst,
                                                 int* __restrict__ cursor,
                                                 int* __restrict__ ssrc) {
    int shard = blockIdx.x & 7;
    int chunk = blockIdx.x >> 3;
    int lo = SHN * shard, hi = lo + SHN;
    const int4* s4 = (const int4*)src;
    const int4* d4 = (const int4*)dst;
    const int nvec = EE / 4;
    for (int i = chunk * 256 + threadIdx.x; i < nvec; i += 256 * 256) {
        int4 d = d4[i];
        int4 s = s4[i];
        if (d.x >= lo && d.x < hi) ssrc[atomicAdd(&cursor[d.x], 1)] = s.x;
        if (d.y >= lo && d.y < hi) ssrc[atomicAdd(&cursor[d.y], 1)] = s.y;
        if (d.z >= lo && d.z < hi) ssrc[atomicAdd(&cursor[d.z], 1)] = s.z;
        if (d.w >= lo && d.w < hi) ssrc[atomicAdd(&cursor[d.w], 1)] = s.w;
    }
}

// ---------------- x -> bf16 ----------------
__global__ void k_cvt(const float* __restrict__ x, unsigned short* __restrict__ xb) {
    int i = blockIdx.x * 256 + threadIdx.x;
    if (i < NN * (HH / 4)) {
        float4 v = ((const float4*)x)[i];
        ushort4 o;
        o.x = f2bf(v.x); o.y = f2bf(v.y); o.z = f2bf(v.z); o.w = f2bf(v.w);
        ((ushort4*)xb)[i] = o;
    }
}

// ---------------- GEMM: C[N,128] = A[N,128] @ W[128,128], MFMA bf16, split-W ----------------
__global__ __launch_bounds__(256) void gemm_mfma(const unsigned short* __restrict__ A,
                                                 const float* __restrict__ W,
                                                 unsigned short* __restrict__ C, int nrows) {
    __shared__ unsigned short smem[2 * 64 * 136];  // WtH | WtL ; reused as Cs[128][68]
    unsigned short* WtH = smem;
    unsigned short* WtL = smem + 64 * 136;

    int t = threadIdx.x;
    int row0 = blockIdx.x * 128;
    int c0   = blockIdx.y * 64;

    for (int idx = t; idx < 64 * 128; idx += 256) {
        int k = idx >> 6, c = idx & 63;
        float w = W[k * 128 + c0 + c];
        unsigned short hb = f2bf(w);
        unsigned short lb = f2bf(w - bf2f(hb));
        WtH[c * 136 + k] = hb;
        WtL[c * 136 + k] = lb;
    }
    __syncthreads();

    int wv = t >> 6, lane = t & 63, m = lane & 15, q = lane >> 4;
    long rowA = row0 + wv * 32 + m;
    long rowB = rowA + 16;

    f32x4 acc[2][4] = {};
    for (int kc = 0; kc < 4; ++kc) {
        int ko = kc * 32 + q * 8;
        short8 a0 = {}, a1 = {};
        if (rowA < nrows) a0 = *(const short8*)(A + rowA * 128 + ko);
        if (rowB < nrows) a1 = *(const short8*)(A + rowB * 128 + ko);
#pragma unroll
        for (int ct = 0; ct < 4; ++ct) {
            short8 bh = *(const short8*)(WtH + (ct * 16 + m) * 136 + ko);
            short8 bl = *(const short8*)(WtL + (ct * 16 + m) * 136 + ko);
            acc[0][ct] = __builtin_amdgcn_mfma_f32_16x16x32_bf16(a0, bh, acc[0][ct], 0, 0, 0);
            acc[0][ct] = __builtin_amdgcn_mfma_f32_16x16x32_bf16(a0, bl, acc[0][ct], 0, 0, 0);
            acc[1][ct] = __builtin_amdgcn_mfma_f32_16x16x32_bf16(a1, bh, acc[1][ct], 0, 0, 0);
            acc[1][ct] = __builtin_amdgcn_mfma_f32_16x16x32_bf16(a1, bl, acc[1][ct], 0, 0, 0);
        }
    }

    __syncthreads();
    unsigned short* Cs = smem;  // [128][68]
#pragma unroll
    for (int rt = 0; rt < 2; ++rt)
#pragma unroll
        for (int ct = 0; ct < 4; ++ct)
#pragma unroll
            for (int r = 0; r < 4; ++r) {
                int rl = wv * 32 + rt * 16 + q * 4 + r;
                Cs[rl * 68 + ct * 16 + m] = f2bf(acc[rt][ct][r]);
            }
    __syncthreads();
    for (int idx = t; idx < 128 * 16; idx += 256) {
        int row = idx >> 4, ch = idx & 15;
        long grow = row0 + row;
        if (grow < nrows)
            *(ushort4*)(C + grow * 128 + c0 + ch * 4) = *(const ushort4*)(Cs + row * 68 + ch * 4);
    }
}

// ---------------- aggregate + bias + BN + ReLU ----------------
// R4 lesson: half-wave scheme had 32 lanes redundantly computing identical
// per-edge metadata (ssrc/dinv loads, mask, 64-bit addr) -> VALUBusy 61%.
// New: one edge per FULL wave. 64 edges of metadata preloaded cooperatively
// (1 ssrc vec-load + 1 dinv gather per 64 edges), per edge readlane -> SGPR
// row base -> saddr loads; 2 ch/lane (uint = full 256 B row per wave);
// packed float2 FMA; pad granularity 8 (ds=0, row n) instead of 16.
__global__ __launch_bounds__(256) void k_agg(const unsigned short* __restrict__ hw,
                                             const int* __restrict__ rp,
                                             const int* __restrict__ ssrc,
                                             const float* __restrict__ dinv,
                                             const float* __restrict__ bsl,
                                             const float* __restrict__ gamma,
                                             const float* __restrict__ beta,
                                             const float* __restrict__ rm,
                                             const float* __restrict__ rv,
                                             unsigned short* __restrict__ out) {
    int lane = threadIdx.x & 63;
    int c2   = lane * 2;                       // 2 channels per lane
    int n = blockIdx.x * 4 + (threadIdx.x >> 6);
    if (n >= NN) return;
    int beg = rp[n], end = rp[n + 1];

    v2f acc0 = {0.f, 0.f}, acc1 = {0.f, 0.f};

    for (int chunk = beg; chunk < end; chunk += 64) {
        int l = chunk + lane;
        bool valid = (l < end);
        int   e  = valid ? ssrc[l] : n;        // pad: self row (harmless, ds=0)
        float dv = valid ? dinv[e] : 0.f;
        int cnt = end - chunk;
        if (cnt > 64) cnt = 64;
        for (int jb = 0; jb < cnt; jb += 8) {
#pragma unroll
            for (int j = 0; j < 8; ++j) {
                int s    = __builtin_amdgcn_readlane(e, jb + j);
                float ds = __int_as_float(
                               __builtin_amdgcn_readlane(__float_as_int(dv), jb + j));
                unsigned u = *(const unsigned*)(hw + (size_t)s * HH + c2);
                v2f vv;
                vv.x = __int_as_float((int)(u << 16));
                vv.y = __int_as_float((int)(u & 0xffff0000u));
                v2f d2 = {ds, ds};
                if (j & 1) acc1 += d2 * vv;
                else       acc0 += d2 * vv;
            }
        }
    }
    v2f a = acc0 + acc1;

    // self-loop
    float di = dinv[n];
    {
        unsigned u = *(const unsigned*)(hw + (size_t)n * HH + c2);
        v2f vv;
        vv.x = __int_as_float((int)(u << 16));
        vv.y = __int_as_float((int)(u & 0xffff0000u));
        v2f d2 = {di, di};
        a += d2 * vv;
    }
    a.x *= di;
    a.y *= di;

    // BN(eval) + bias + ReLU for channels c2, c2+1
    float g0 = gamma[c2],   g1 = gamma[c2 + 1];
    float r0 = rv[c2],      r1 = rv[c2 + 1];
    float s0 = g0 * rsqrtf(r0 + EPSV);
    float s1 = g1 * rsqrtf(r1 + EPSV);
    float b0 = fmaf(bsl[c2]     - rm[c2],     s0, beta[c2]);
    float b1 = fmaf(bsl[c2 + 1] - rm[c2 + 1], s1, beta[c2 + 1]);
    float y0 = fmaxf(fmaf(a.x, s0, b0), 0.f);
    float y1 = fmaxf(fmaf(a.y, s1, b1), 0.f);
    ushort2 o;
    o.x = f2bf(y0);
    o.y = f2bf(y1);
    *(ushort2*)(out + (size_t)n * HH + c2) = o;
}

// ---------------- global mean pool (batch sorted, bf16 input) ----------------
__global__ __launch_bounds__(128) void k_pool(const unsigned short* __restrict__ h,
                                              const int* __restrict__ batch,
                                              float* __restrict__ pooled,
                                              float* __restrict__ cnt) {
    int t = threadIdx.x;
    const int chunk = (NN + 1023) / 1024;
    int n0 = blockIdx.x * chunk;
    if (n0 >= NN) return;
    int n1 = n0 + chunk;
    if (n1 > NN) n1 = NN;
    int cur = batch[n0];
    float acc = 0.f;
    int k = 0;
    for (int n = n0; n < n1; ++n) {
        int b = batch[n];
        if (b != cur) {
            atomicAdd(&pooled[(size_t)cur * 128 + t], acc);
            if (t == 0) atomicAdd(&cnt[cur], (float)k);
            acc = 0.f; k = 0; cur = b;
        }
        acc += bf2f(h[(size_t)n * 128 + t]);
        ++k;
    }
    atomicAdd(&pooled[(size_t)cur * 128 + t], acc);
    if (t == 0) atomicAdd(&cnt[cur], (float)k);
}

// ---------------- LSTM (single step, h0=c0=0) + FC ----------------
__global__ __launch_bounds__(128) void k_head(const float* __restrict__ pooled,
                                              const float* __restrict__ cnt,
                                              const float* __restrict__ W_ih,
                                              const float* __restrict__ b_ih,
                                              const float* __restrict__ b_hh,
                                              const float* __restrict__ W_fc,
                                              const float* __restrict__ b_fc,
                                              float* __restrict__ out) {
    __shared__ float pm[128];
    __shared__ float gate[512];
    __shared__ float hn[128];
    int g = blockIdx.x, t = threadIdx.x;
    float cdiv = fmaxf(cnt[g], 1.0f);
    pm[t] = pooled[(size_t)g * 128 + t] / cdiv;
    __syncthreads();
    for (int j = t; j < 512; j += 128) {
        float acc = b_ih[j] + b_hh[j];
        const float* w = W_ih + (size_t)j * 128;
#pragma unroll 8
        for (int k = 0; k < 128; ++k) acc = fmaf(pm[k], w[k], acc);
        gate[j] = acc;
    }
    __syncthreads();
    {
        float gi = gate[t], gg = gate[256 + t], go = gate[384 + t];
        float cc = (1.f / (1.f + expf(-gi))) * tanhf(gg);
        hn[t] = (1.f / (1.f + expf(-go))) * tanhf(cc);
    }
    __syncthreads();
    if (t < 16) {
        float acc = b_fc[t];
        const float* w = W_fc + (size_t)t * 128;
#pragma unroll 8
        for (int k = 0; k < 128; ++k) acc = fmaf(hn[k], w[k], acc);
        out[(size_t)g * 16 + t] = acc;
    }
}

// ---------------- launch ----------------
extern "C" void kernel_launch(void* const* d_in, const int* in_sizes, int n_in,
                              void* d_out, int out_size, void* d_ws, size_t ws_size,
                              hipStream_t stream) {
    const float* x      = (const float*)d_in[0];
    const int*   ei     = (const int*)d_in[1];
    const int*   src    = ei;
    const int*   dst    = ei + EE;
    const int*   batch  = (const int*)d_in[2];
    const float* Ws     = (const float*)d_in[3];
    const float* bs     = (const float*)d_in[4];
    const float* gammas = (const float*)d_in[5];
    const float* betas  = (const float*)d_in[6];
    const float* rms    = (const float*)d_in[7];
    const float* rvs    = (const float*)d_in[8];
    const float* W_ih   = (const float*)d_in[9];
    // d_in[10] = W_hh (unused: h0 = 0)
    const float* b_ih   = (const float*)d_in[11];
    const float* b_hh   = (const float*)d_in[12];
    const float* W_fc   = (const float*)d_in[13];
    const float* b_fc   = (const float*)d_in[14];
    float* out = (float*)d_out;

    char* w = (char*)d_ws;
    int*            deg    = (int*)(w + OFF_DEG);
    float*          dinv   = (float*)(w + OFF_DNV);
    int*            rp     = (int*)(w + OFF_RP);
    int*            cursor = (int*)(w + OFF_CUR);
    int*            ssrc   = (int*)(w + OFF_SRC);
    int*            bsum   = (int*)(w + OFF_BS);
    unsigned short* xb     = (unsigned short*)(w + OFF_XB);
    unsigned short* hwb    = (unsigned short*)(w + OFF_HW);
    unsigned short* h0     = (unsigned short*)(w + OFF_H0);
    float*          pooled = (float*)(w + OFF_PL);
    float*          cntb   = pooled + (size_t)GG * HH;

    hipMemsetAsync(deg, 0, (size_t)NN * 4, stream);
    hipMemsetAsync(pooled, 0, ((size_t)GG * HH + GG) * 4, stream);

    k_count<<<2048, 256, 0, stream>>>(dst, deg);
    const int nscan = (NN + 1023) / 1024;
    k_scan_local<<<nscan, 1024, 0, stream>>>(deg, rp, bsum);
    k_scan_blocks<<<1, 128, 0, stream>>>(bsum, nscan);
    k_scan_add<<<(NN + 255) / 256, 256, 0, stream>>>(rp, bsum, cursor);
    k_dinv<<<(NN + 255) / 256, 256, 0, stream>>>(deg, dinv);
    k_scatter<<<2048, 256, 0, stream>>>(src, dst, cursor, ssrc);
    k_cvt<<<(NN * 32 + 255) / 256, 256, 0, stream>>>(x, xb);

    const unsigned short* hin = xb;
    dim3 ggrid((NN + 127) / 128, 2);
    for (int l = 0; l < 3; ++l) {
        gemm_mfma<<<ggrid, 256, 0, stream>>>(hin, Ws + (size_t)l * 128 * 128, hwb, NN);
        k_agg<<<(NN + 3) / 4, 256, 0, stream>>>(hwb, rp, ssrc, dinv,
                                                bs + l * 128, gammas + l * 128, betas + l * 128,
                                                rms + l * 128, rvs + l * 128, h0);
        hin = h0;
    }
    k_pool<<<1024, 128, 0, stream>>>(h0, batch, pooled, cntb);
    k_head<<<GG, 128, 0, stream>>>(pooled, cntb, W_ih, b_ih, b_hh, W_fc, b_fc, out);
}